// Round 4
// baseline (233.553 us; speedup 1.0000x reference)
//
#include <hip/hip_runtime.h>
#include <hip/hip_cooperative_groups.h>
#include <math.h>

namespace cg = cooperative_groups;

// S4 diagonal SSM: B=2, L=2048, H=512, N=64. Chunked: T=64, NC=32.
// Single cooperative kernel, 512 blocks x 256 threads (2 blocks/CU co-resident):
//   Phase A: xlocal end-states per chunk (+ table setup on tid<32768)
//   Phase B: chunk-state scan (tid<65536)
//   Phase C: y = causal block-conv(K,u) + C*Ad^(t'+1)*S_c   (RT=16 t' per thread)

#define BATCH   2
#define SEQLEN  2048
#define DMODEL  512
#define DSTATE  64
#define T_CHUNK 64
#define NCHUNK  32
#define RT      16

__device__ __forceinline__ float A_cont(int n) {
    // A[n] = (1 + (n+1)/64)^(-1/2)
    return rsqrtf(1.0f + (float)(n + 1) * (1.0f / 64.0f));
}

__global__ __launch_bounds__(256, 2) void k_fused(const float* __restrict__ u,
                                                  const float* __restrict__ B_re,
                                                  const float* __restrict__ C_re,
                                                  const float* __restrict__ log_dt,
                                                  const float* __restrict__ Dp,
                                                  float* __restrict__ Kbuf,     // [64][512]
                                                  float* __restrict__ AdTab,    // [64][512]
                                                  float* __restrict__ CpStep,   // [4][64][512]
                                                  float* __restrict__ xl,       // [2][32][64][512]
                                                  float* __restrict__ out) {
    cg::grid_group grid = cg::this_grid();
    int tid = blockIdx.x * 256 + threadIdx.x;      // 0..131071

    // ---------------- Phase A: xlocal (all threads; 16 states each) ----------------
    {
        int h  = tid & (DMODEL - 1);
        int ng = (tid >> 9) & 3;                   // 16 n per group
        int c  = (tid >> 11) & (NCHUNK - 1);
        int b  = tid >> 16;
        float delta = expf(log_dt[h]);
        float Ad[16], Bd[16], x[16];
        #pragma unroll
        for (int nn = 0; nn < 16; ++nn) {
            int n = ng * 16 + nn;
            float dA = delta * A_cont(n);
            Ad[nn] = expf(dA);
            Bd[nn] = expm1f(dA) * B_re[n] * delta;
            x[nn] = 0.0f;
        }
        const float* up = u + ((size_t)(b * SEQLEN + c * T_CHUNK)) * DMODEL + h;
        #pragma unroll 4
        for (int s = 0; s < T_CHUNK; ++s) {
            float uv = up[(size_t)s * DMODEL];     // coalesced in h
            #pragma unroll
            for (int nn = 0; nn < 16; ++nn)
                x[nn] = fmaf(Ad[nn], x[nn], Bd[nn] * uv);
        }
        float* xp = xl + ((size_t)((b * NCHUNK + c) * DSTATE + ng * 16)) * DMODEL + h;
        #pragma unroll
        for (int nn = 0; nn < 16; ++nn) xp[(size_t)nn * DMODEL] = x[nn];
    }
    // ---------------- Phase A': tables (tid < 32768: thread (j,h)) ----------------
    if (tid < 32768) {
        int h = tid & (DMODEL - 1);
        int j = tid >> 9;                          // 0..63
        float delta = expf(log_dt[h]);
        float Adj = expf(delta * A_cont(j));
        AdTab[j * DMODEL + h] = Adj;
        float sq = Adj * Adj; sq = sq * sq; sq = sq * sq;
        float e16 = sq * sq;                       // Adj^16
        float p = C_re[j] * Adj;                   // C*Ad^1
        #pragma unroll
        for (int i = 0; i < 4; ++i) {
            CpStep[(i * DSTATE + j) * DMODEL + h] = p;  // C*Ad^(16i+1)
            p *= e16;
        }
        float acc = (j == 0) ? Dp[h] : 0.0f;       // D folded into K[0]
        for (int n = 0; n < DSTATE; ++n) {
            float dAn = delta * A_cont(n);
            float Bd = expm1f(dAn) * B_re[n] * delta;
            acc = fmaf(C_re[n] * Bd, expf(dAn * (float)j), acc);
        }
        Kbuf[j * DMODEL + h] = acc;
    }

    grid.sync();

    // ---------------- Phase B: chunk-state scan (tid < 65536) ----------------
    // After: xl[b][c-1][n][h] holds S_c (state entering chunk c).
    if (tid < 65536) {
        int h = tid & (DMODEL - 1);
        int n = (tid >> 9) & (DSTATE - 1);
        int b = tid >> 15;
        float delta = expf(log_dt[h]);
        float ApT = expf(delta * A_cont(n) * (float)T_CHUNK);  // A_d^T
        float* base = xl + ((size_t)(b * NCHUNK * DSTATE + n)) * DMODEL + h;
        float v[NCHUNK - 1];
        #pragma unroll
        for (int c = 0; c < NCHUNK - 1; ++c)
            v[c] = base[(size_t)c * DSTATE * DMODEL];
        float s = 0.0f;
        #pragma unroll
        for (int c = 0; c < NCHUNK - 1; ++c) { s = fmaf(ApT, s, v[c]); v[c] = s; }
        #pragma unroll
        for (int c = 0; c < NCHUNK - 1; ++c)
            base[(size_t)c * DSTATE * DMODEL] = v[c];
    }

    grid.sync();

    // ---------------- Phase C: output, 16 t' x 1 h per thread ----------------
    {
        int h   = tid & (DMODEL - 1);
        int it4 = (tid >> 9) & 3;                  // t'-tile of 16 (block-uniform)
        int c   = (tid >> 11) & (NCHUNK - 1);
        int b   = tid >> 16;
        int tp0 = it4 * RT;

        const float* ub = u + ((size_t)(b * SEQLEN + c * T_CHUNK)) * DMODEL + h;
        const float* kb = Kbuf + h;

        float acc[RT];
        #pragma unroll
        for (int i = 0; i < RT; ++i) acc[i] = 0.0f;

        // full 16x16 source blocks: 47 loads -> 256 FMA each
        for (int sb = 0; sb < it4; ++sb) {
            float ureg[16], krow[31];
            int base = tp0 - sb * 16 - 15;         // >= 1
            #pragma unroll
            for (int q = 0; q < 16; ++q) ureg[q] = ub[(size_t)(sb * 16 + q) * DMODEL];
            #pragma unroll
            for (int j = 0; j < 31; ++j) krow[j] = kb[(size_t)(base + j) * DMODEL];
            #pragma unroll
            for (int q = 0; q < 16; ++q)
                #pragma unroll
                for (int i = 0; i < RT; ++i)
                    acc[i] = fmaf(krow[i - q + 15], ureg[q], acc[i]);  // K[tp0+i-(sb*16+q)]
        }
        // diagonal (causal) block: 32 loads -> 136 FMA
        {
            float ureg[16], krow[16];
            #pragma unroll
            for (int q = 0; q < 16; ++q) ureg[q] = ub[(size_t)(tp0 + q) * DMODEL];
            #pragma unroll
            for (int j = 0; j < 16; ++j) krow[j] = kb[(size_t)j * DMODEL];
            #pragma unroll
            for (int q = 0; q < 16; ++q)
                #pragma unroll
                for (int i = 0; i < RT; ++i)
                    if (i >= q) acc[i] = fmaf(krow[i - q], ureg[q], acc[i]);
        }
        // chunk-entry-state correction: acc[i] += sum_n C*Ad^(tp0+i+1) * S[n]
        if (c > 0) {
            const float* sp = xl + ((size_t)((b * NCHUNK + (c - 1)) * DSTATE)) * DMODEL + h;
            const float* ap = AdTab + h;
            const float* cp = CpStep + (size_t)(it4 * DSTATE) * DMODEL + h;
            #pragma unroll 4
            for (int n = 0; n < DSTATE; ++n) {
                float Sv  = sp[(size_t)n * DMODEL];
                float Adv = ap[(size_t)n * DMODEL];
                float w   = cp[(size_t)n * DMODEL] * Sv;
                acc[0] += w;
                #pragma unroll
                for (int i = 1; i < RT; ++i) { w *= Adv; acc[i] += w; }
            }
        }
        float* ob = out + ((size_t)(b * SEQLEN + c * T_CHUNK + tp0)) * DMODEL + h;
        #pragma unroll
        for (int i = 0; i < RT; ++i) ob[(size_t)i * DMODEL] = acc[i];
    }
}

extern "C" void kernel_launch(void* const* d_in, const int* in_sizes, int n_in,
                              void* d_out, int out_size, void* d_ws, size_t ws_size,
                              hipStream_t stream) {
    const float* u      = (const float*)d_in[0];
    const float* B_re   = (const float*)d_in[1];
    const float* C_re   = (const float*)d_in[2];
    const float* log_dt = (const float*)d_in[3];
    const float* D      = (const float*)d_in[4];
    float* out = (float*)d_out;
    float* ws  = (float*)d_ws;

    // ws layout (floats):
    float* Kbuf   = ws;                            // 64*512   = 32768
    float* AdTab  = ws + 32768;                    // 64*512   = 32768
    float* CpStep = ws + 65536;                    // 4*64*512 = 131072
    float* xl     = ws + 65536 + 131072;           // 2*32*64*512 = 2097152

    void* args[] = {(void*)&u, (void*)&B_re, (void*)&C_re, (void*)&log_dt, (void*)&D,
                    (void*)&Kbuf, (void*)&AdTab, (void*)&CpStep, (void*)&xl, (void*)&out};
    hipLaunchCooperativeKernel((const void*)k_fused, dim3(512), dim3(256), args, 0, stream);
}

// Round 5
// 108.510 us; speedup vs baseline: 2.1524x; 2.1524x over previous
//
#include <hip/hip_runtime.h>
#include <math.h>

// S4 diagonal SSM: B=2, L=2048, H=512, N=64. Chunked: T=64, NC=32.
//   y[cT+t'] = sum_{tau<=t'} K[h,tau]*u[t-tau] + sum_n C[n]*Ad^(t'+1)*S_c[b,n,h]
//   K[h,tau] = sum_n C[n]*Bd[h,n]*Ad[h,n]^tau  (D folded into K[0])
//   S_c via per-chunk local end-states + fully-unrolled chunk scan.
// 3 kernels (cooperative grid.sync measured 70+us/sync on gfx950 -- do not fuse).

#define BATCH   2
#define SEQLEN  2048
#define DMODEL  512
#define DSTATE  64
#define T_CHUNK 64
#define NCHUNK  32
#define RT      16

__device__ __forceinline__ float A_cont(int n) {
    // A[n] = (1 + (n+1)/64)^(-1/2)
    return rsqrtf(1.0f + (float)(n + 1) * (1.0f / 64.0f));
}

// ---------------- Kernel 1: xlocal[b][c][n][h] (16 states/thread) ----------------
__global__ __launch_bounds__(256) void k_xlocal(const float* __restrict__ u,
                                                const float* __restrict__ B_re,
                                                const float* __restrict__ log_dt,
                                                float* __restrict__ xl) {
    int tid = blockIdx.x * 256 + threadIdx.x;      // 131072 threads
    int h  = tid & (DMODEL - 1);
    int ng = (tid >> 9) & 3;                       // 16 n per group
    int c  = (tid >> 11) & (NCHUNK - 1);
    int b  = tid >> 16;
    float delta = expf(log_dt[h]);
    float Ad[16], Bd[16], x[16];
    #pragma unroll
    for (int nn = 0; nn < 16; ++nn) {
        int n = ng * 16 + nn;
        float dA = delta * A_cont(n);
        Ad[nn] = expf(dA);
        Bd[nn] = expm1f(dA) * B_re[n] * delta;
        x[nn] = 0.0f;
    }
    const float* up = u + ((size_t)(b * SEQLEN + c * T_CHUNK)) * DMODEL + h;
    #pragma unroll 4
    for (int s = 0; s < T_CHUNK; ++s) {
        float uv = up[(size_t)s * DMODEL];         // coalesced in h
        #pragma unroll
        for (int nn = 0; nn < 16; ++nn)
            x[nn] = fmaf(Ad[nn], x[nn], Bd[nn] * uv);
    }
    float* xp = xl + ((size_t)((b * NCHUNK + c) * DSTATE + ng * 16)) * DMODEL + h;
    #pragma unroll
    for (int nn = 0; nn < 16; ++nn) xp[(size_t)nn * DMODEL] = x[nn];
}

// ---------------- Kernel 2: chunk scan (unrolled) + table setup ----------------
// Scan: after this, xl[b][c-1][n][h] holds S_c (state entering chunk c).
// Setup (tid<32768): Kbuf[64][512] (D folded at tau=0), AdTab[64][512],
//                    CpStep[4][64][512] = C*Ad^(16i+1).
__global__ __launch_bounds__(256) void k_scanset(const float* __restrict__ B_re,
                                                 const float* __restrict__ C_re,
                                                 const float* __restrict__ log_dt,
                                                 const float* __restrict__ Dp,
                                                 float* __restrict__ xl,
                                                 float* __restrict__ Kbuf,
                                                 float* __restrict__ AdTab,
                                                 float* __restrict__ CpStep) {
    int tid = blockIdx.x * 256 + threadIdx.x;      // 65536 threads
    {
        int h = tid & (DMODEL - 1);
        int n = (tid >> 9) & (DSTATE - 1);
        int b = tid >> 15;
        float delta = expf(log_dt[h]);
        float ApT = expf(delta * A_cont(n) * (float)T_CHUNK);  // Ad^T
        float* base = xl + ((size_t)(b * NCHUNK * DSTATE + n)) * DMODEL + h;
        float v[NCHUNK - 1];
        #pragma unroll
        for (int c = 0; c < NCHUNK - 1; ++c)
            v[c] = base[(size_t)c * DSTATE * DMODEL];          // 31 independent loads
        float s = 0.0f;
        #pragma unroll
        for (int c = 0; c < NCHUNK - 1; ++c) { s = fmaf(ApT, s, v[c]); v[c] = s; }
        #pragma unroll
        for (int c = 0; c < NCHUNK - 1; ++c)
            base[(size_t)c * DSTATE * DMODEL] = v[c];
    }
    if (tid < 32768) {
        int h = tid & (DMODEL - 1);
        int j = tid >> 9;                          // 0..63
        float delta = expf(log_dt[h]);
        float Adj = expf(delta * A_cont(j));
        AdTab[j * DMODEL + h] = Adj;
        float sq = Adj * Adj; sq = sq * sq; sq = sq * sq;
        float e16 = sq * sq;                       // Adj^16
        float p = C_re[j] * Adj;                   // C*Ad^1
        #pragma unroll
        for (int i = 0; i < 4; ++i) {
            CpStep[(i * DSTATE + j) * DMODEL + h] = p;
            p *= e16;
        }
        float acc = (j == 0) ? Dp[h] : 0.0f;       // D folded into K[0]
        for (int n = 0; n < DSTATE; ++n) {
            float dAn = delta * A_cont(n);
            float Bd = expm1f(dAn) * B_re[n] * delta;
            acc = fmaf(C_re[n] * Bd, expf(dAn * (float)j), acc);
        }
        Kbuf[j * DMODEL + h] = acc;
    }
}

// ---------------- Kernel 3: output, 16 t' per thread, 16x16 block conv ----------------
__global__ __launch_bounds__(256) void k_out(const float* __restrict__ u,
                                             const float* __restrict__ Kbuf,
                                             const float* __restrict__ AdTab,
                                             const float* __restrict__ CpStep,
                                             const float* __restrict__ Sbuf,
                                             float* __restrict__ out) {
    int tid = blockIdx.x * 256 + threadIdx.x;      // 131072 threads
    int h   = tid & (DMODEL - 1);
    int it4 = (tid >> 9) & 3;                      // t'-tile of 16 (block-uniform)
    int c   = (tid >> 11) & (NCHUNK - 1);
    int b   = tid >> 16;
    int tp0 = it4 * RT;

    const float* ub = u + ((size_t)(b * SEQLEN + c * T_CHUNK)) * DMODEL + h;
    const float* kb = Kbuf + h;

    float acc[RT];
    #pragma unroll
    for (int i = 0; i < RT; ++i) acc[i] = 0.0f;

    // full 16x16 source blocks: 47 loads -> 256 FMA each (compile-time indices)
    for (int sb = 0; sb < it4; ++sb) {
        float ureg[16], krow[31];
        int base = tp0 - sb * 16 - 15;             // >= 1
        #pragma unroll
        for (int q = 0; q < 16; ++q) ureg[q] = ub[(size_t)(sb * 16 + q) * DMODEL];
        #pragma unroll
        for (int j = 0; j < 31; ++j) krow[j] = kb[(size_t)(base + j) * DMODEL];
        #pragma unroll
        for (int q = 0; q < 16; ++q)
            #pragma unroll
            for (int i = 0; i < RT; ++i)
                acc[i] = fmaf(krow[i - q + 15], ureg[q], acc[i]);   // K[tp0+i-(sb*16+q)]
    }
    // diagonal (causal) block: 32 loads -> 136 FMA
    {
        float ureg[16], krow[16];
        #pragma unroll
        for (int q = 0; q < 16; ++q) ureg[q] = ub[(size_t)(tp0 + q) * DMODEL];
        #pragma unroll
        for (int j = 0; j < 16; ++j) krow[j] = kb[(size_t)j * DMODEL];
        #pragma unroll
        for (int q = 0; q < 16; ++q)
            #pragma unroll
            for (int i = 0; i < RT; ++i)
                if (i >= q) acc[i] = fmaf(krow[i - q], ureg[q], acc[i]);
    }
    // chunk-entry-state correction: acc[i] += sum_n C*Ad^(tp0+i+1) * S[n]
    if (c > 0) {
        const float* sp = Sbuf + ((size_t)((b * NCHUNK + (c - 1)) * DSTATE)) * DMODEL + h;
        const float* ap = AdTab + h;
        const float* cp = CpStep + (size_t)(it4 * DSTATE) * DMODEL + h;
        #pragma unroll 4
        for (int n = 0; n < DSTATE; ++n) {
            float Sv  = sp[(size_t)n * DMODEL];
            float Adv = ap[(size_t)n * DMODEL];
            float w   = cp[(size_t)n * DMODEL] * Sv;
            acc[0] += w;
            #pragma unroll
            for (int i = 1; i < RT; ++i) { w *= Adv; acc[i] += w; }
        }
    }
    float* ob = out + ((size_t)(b * SEQLEN + c * T_CHUNK + tp0)) * DMODEL + h;
    #pragma unroll
    for (int i = 0; i < RT; ++i) ob[(size_t)i * DMODEL] = acc[i];
}

extern "C" void kernel_launch(void* const* d_in, const int* in_sizes, int n_in,
                              void* d_out, int out_size, void* d_ws, size_t ws_size,
                              hipStream_t stream) {
    const float* u      = (const float*)d_in[0];
    const float* B_re   = (const float*)d_in[1];
    const float* C_re   = (const float*)d_in[2];
    const float* log_dt = (const float*)d_in[3];
    const float* D      = (const float*)d_in[4];
    float* out = (float*)d_out;
    float* ws  = (float*)d_ws;

    // ws layout (floats):
    float* Kbuf   = ws;                            // 64*512   = 32768
    float* AdTab  = ws + 32768;                    // 64*512   = 32768
    float* CpStep = ws + 65536;                    // 4*64*512 = 131072
    float* xl     = ws + 65536 + 131072;           // 2*32*64*512 = 2097152

    k_xlocal <<<512, 256, 0, stream>>>(u, B_re, log_dt, xl);
    k_scanset<<<256, 256, 0, stream>>>(B_re, C_re, log_dt, D, xl, Kbuf, AdTab, CpStep);
    k_out    <<<512, 256, 0, stream>>>(u, Kbuf, AdTab, CpStep, xl, out);
}